// Round 1
// baseline (1114.213 us; speedup 1.0000x reference)
//
#include <hip/hip_runtime.h>
#include <math.h>

#define NN 100000
#define NE 1600000
#define NG 64
#define F  128

constexpr int SCAN_CHUNK = 1024;                       // 256 threads * 4
constexpr int NB_SCAN = (NN + SCAN_CHUNK - 1) / SCAN_CHUNK;  // 98
constexpr int TM = 128;                                // GEMM rows per block
constexpr int GEMM_LDS = (TM * F + F * F) * 4;         // 128 KiB

// ---------------- degree count ----------------
__global__ __launch_bounds__(256) void k_count(const int* __restrict__ dst, int* __restrict__ cnt) {
    int e = blockIdx.x * 256 + threadIdx.x;
    if (e < NE) atomicAdd(&cnt[dst[e]], 1);
}

__global__ __launch_bounds__(256) void k_dinv(const int* __restrict__ cnt, float* __restrict__ dinv) {
    int i = blockIdx.x * 256 + threadIdx.x;
    if (i < NN) dinv[i] = rsqrtf((float)cnt[i] + 1.0f);
}

// ---------------- prefix scan (3 kernels) ----------------
__global__ __launch_bounds__(256) void k_scan1(const int* __restrict__ cnt, int* __restrict__ bsum) {
    __shared__ int sh[256];
    int b = blockIdx.x, t = threadIdx.x;
    int base = b * SCAN_CHUNK + t * 4;
    int s = 0;
#pragma unroll
    for (int u = 0; u < 4; ++u) { int i = base + u; if (i < NN) s += cnt[i]; }
    sh[t] = s; __syncthreads();
    for (int d = 128; d > 0; d >>= 1) { if (t < d) sh[t] += sh[t + d]; __syncthreads(); }
    if (t == 0) bsum[b] = sh[0];
}

__global__ __launch_bounds__(128) void k_scan2(const int* __restrict__ bsum, int* __restrict__ boff) {
    __shared__ int sh[128];
    int t = threadIdx.x;
    int v = (t < NB_SCAN) ? bsum[t] : 0;
    sh[t] = v; __syncthreads();
    for (int d = 1; d < 128; d <<= 1) {
        int x = (t >= d) ? sh[t - d] : 0;
        __syncthreads();
        sh[t] += x;
        __syncthreads();
    }
    if (t < NB_SCAN) boff[t] = sh[t] - v;  // exclusive
}

__global__ __launch_bounds__(256) void k_scan3(const int* __restrict__ cnt, const int* __restrict__ boff,
                                               int* __restrict__ row_start, int* __restrict__ cursor) {
    __shared__ int sh[256];
    int b = blockIdx.x, t = threadIdx.x;
    int base = b * SCAN_CHUNK + t * 4;
    int v[4]; int sum = 0;
#pragma unroll
    for (int u = 0; u < 4; ++u) { int i = base + u; v[u] = (i < NN) ? cnt[i] : 0; sum += v[u]; }
    sh[t] = sum; __syncthreads();
    for (int d = 1; d < 256; d <<= 1) {
        int x = (t >= d) ? sh[t - d] : 0;
        __syncthreads();
        sh[t] += x;
        __syncthreads();
    }
    int run = boff[b] + (sh[t] - sum);
#pragma unroll
    for (int u = 0; u < 4; ++u) {
        int i = base + u;
        if (i < NN) { row_start[i] = run; cursor[i] = run; run += v[u]; }
    }
    if (b == 0 && t == 0) row_start[NN] = NE;
}

__global__ __launch_bounds__(256) void k_scatter(const int* __restrict__ src, const int* __restrict__ dst,
                                                 int* __restrict__ cursor, int* __restrict__ col) {
    int e = blockIdx.x * 256 + threadIdx.x;
    if (e < NE) {
        int d = dst[e];
        int p = atomicAdd(&cursor[d], 1);
        col[p] = src[e];
    }
}

// ---------------- W transpose (Wt[c][k] = W[k][c]) ----------------
__global__ __launch_bounds__(256) void k_transpose(const float* __restrict__ W, float* __restrict__ Wt) {
    int idx = blockIdx.x * 256 + threadIdx.x;
    int k = idx >> 7, c = idx & 127;
    Wt[c * F + k] = W[idx];
}

// ---------------- fp32 GEMM: C[M,128] = A[M,128] @ W[128,128] ----------------
// 128x128 tile per block, 256 threads, 8x8 per thread, swizzled LDS (conflict-free/2-way).
__global__ __launch_bounds__(256, 1) void k_gemm(const float* __restrict__ A, const float* __restrict__ Wt,
                                                 float* __restrict__ C) {
    extern __shared__ float smem[];
    float* As = smem;            // [128][128] swizzled: elem k at (k + 4*(r>>3)) & 127
    float* Ws = smem + TM * F;   // [128][128] swizzled: elem k at (k + 4*(c>>3)) & 127
    int tid = threadIdx.x;
    int row0 = blockIdx.x * TM;

#pragma unroll
    for (int it = 0; it < 16; ++it) {
        int idx4 = tid + it * 256;      // 4096 float4 total
        int r = idx4 >> 5;
        int k4 = idx4 & 31;
        int gr = row0 + r;
        float4 val = make_float4(0.f, 0.f, 0.f, 0.f);
        if (gr < NN) val = *(const float4*)&A[(size_t)gr * F + k4 * 4];
        int kk = ((k4 * 4) + 4 * (r >> 3)) & 127;
        *(float4*)&As[r * F + kk] = val;
    }
#pragma unroll
    for (int it = 0; it < 16; ++it) {
        int idx4 = tid + it * 256;
        int c = idx4 >> 5;
        int k4 = idx4 & 31;
        float4 val = *(const float4*)&Wt[c * F + k4 * 4];
        int kk = ((k4 * 4) + 4 * (c >> 3)) & 127;
        *(float4*)&Ws[c * F + kk] = val;
    }
    __syncthreads();

    int rb = (tid >> 4) * 8;
    int cb = (tid & 15) * 8;
    float acc[8][8];
#pragma unroll
    for (int i = 0; i < 8; ++i)
#pragma unroll
        for (int j = 0; j < 8; ++j) acc[i][j] = 0.f;

    for (int k = 0; k < F; k += 4) {
        float4 av[8], wv[8];
#pragma unroll
        for (int i = 0; i < 8; ++i) {
            int r = rb + i;
            av[i] = *(const float4*)&As[r * F + ((k + 4 * (r >> 3)) & 127)];
        }
#pragma unroll
        for (int j = 0; j < 8; ++j) {
            int c = cb + j;
            wv[j] = *(const float4*)&Ws[c * F + ((k + 4 * (c >> 3)) & 127)];
        }
#pragma unroll
        for (int i = 0; i < 8; ++i)
#pragma unroll
            for (int j = 0; j < 8; ++j) {
                acc[i][j] += av[i].x * wv[j].x + av[i].y * wv[j].y + av[i].z * wv[j].z + av[i].w * wv[j].w;
            }
    }

#pragma unroll
    for (int i = 0; i < 8; ++i) {
        int gr = row0 + rb + i;
        if (gr < NN) {
            float4 o0 = make_float4(acc[i][0], acc[i][1], acc[i][2], acc[i][3]);
            float4 o1 = make_float4(acc[i][4], acc[i][5], acc[i][6], acc[i][7]);
            *(float4*)&C[(size_t)gr * F + cb] = o0;
            *(float4*)&C[(size_t)gr * F + cb + 4] = o1;
        }
    }
}

// ---------------- SpMM aggregation + bias + optional ELU ----------------
// block = 1 node, 128 threads = 128 feature columns.
__global__ __launch_bounds__(128) void k_spmm(const float* __restrict__ xw, const int* __restrict__ row_start,
                                              const int* __restrict__ col, const float* __restrict__ dinv,
                                              const float* __restrict__ bias, float* __restrict__ hout,
                                              int do_elu) {
    int i = blockIdx.x;
    int c = threadIdx.x;
    int s = row_start[i], e = row_start[i + 1];
    float acc = 0.f;
    for (int p = s; p < e; ++p) {
        int j = col[p];
        acc += dinv[j] * xw[(size_t)j * F + c];
    }
    float di = dinv[i];
    float v = di * (acc + di * xw[(size_t)i * F + c]) + bias[c];
    if (do_elu) v = (v > 0.f) ? v : (__expf(v) - 1.f);
    hout[(size_t)i * F + c] = v;
}

// ---------------- graph boundaries by binary search ----------------
__global__ __launch_bounds__(128) void k_gstart(const int* __restrict__ batch, int* __restrict__ gstart) {
    int g = threadIdx.x;
    if (g > NG) return;
    if (g == NG) { gstart[NG] = NN; return; }
    int lo = 0, hi = NN;
    while (lo < hi) { int mid = (lo + hi) >> 1; if (batch[mid] < g) lo = mid + 1; else hi = mid; }
    gstart[g] = lo;
}

// ---------------- mean pool (partial sums, atomic combine) ----------------
__global__ __launch_bounds__(128) void k_pool(const float* __restrict__ h, const int* __restrict__ gstart,
                                              float* __restrict__ poolsum) {
    int g = blockIdx.x >> 4, q = blockIdx.x & 15;
    int c = threadIdx.x;
    int s = gstart[g], e = gstart[g + 1];
    int n = e - s;
    int per = (n + 15) >> 4;
    int ss = s + q * per;
    int ee = min(ss + per, e);
    float acc = 0.f;
    for (int i = ss; i < ee; ++i) acc += h[(size_t)i * F + c];
    if (acc != 0.f || true) atomicAdd(&poolsum[g * F + c], acc);
}

// ---------------- final MLP ----------------
__global__ __launch_bounds__(64) void k_mlp(const float* __restrict__ poolsum, const int* __restrict__ gstart,
                                            const float* __restrict__ stats,
                                            const float* __restrict__ fw1, const float* __restrict__ fb1,
                                            const float* __restrict__ fw2, const float* __restrict__ fb2,
                                            const float* __restrict__ fw3, const float* __restrict__ fb3,
                                            float* __restrict__ out) {
    __shared__ float gv[F + 8];
    __shared__ float h1[32];
    __shared__ float h2[16];
    int g = blockIdx.x, t = threadIdx.x;
    float cntf = fmaxf((float)(gstart[g + 1] - gstart[g]), 1.0f);
    for (int c = t; c < F; c += 64) gv[c] = poolsum[g * F + c] / cntf;
    if (t < 8) gv[F + t] = stats[g * 8 + t];
    __syncthreads();
    if (t < 32) {
        float a = fb1[t];
        for (int k = 0; k < F + 8; ++k) a += gv[k] * fw1[k * 32 + t];
        h1[t] = fmaxf(a, 0.f);
    }
    __syncthreads();
    if (t < 16) {
        float a = fb2[t];
        for (int k = 0; k < 32; ++k) a += h1[k] * fw2[k * 16 + t];
        h2[t] = fmaxf(a, 0.f);
    }
    __syncthreads();
    if (t == 0) {
        float a = fb3[0];
        for (int k = 0; k < 16; ++k) a += h2[k] * fw3[k];
        out[g] = a;
    }
}

extern "C" void kernel_launch(void* const* d_in, const int* in_sizes, int n_in,
                              void* d_out, int out_size, void* d_ws, size_t ws_size,
                              hipStream_t stream) {
    const float* x     = (const float*)d_in[0];
    const int*   ei    = (const int*)d_in[1];
    const int*   batch = (const int*)d_in[2];
    const float* stats = (const float*)d_in[3];
    const float* W1 = (const float*)d_in[4];
    const float* b1 = (const float*)d_in[5];
    const float* W2 = (const float*)d_in[6];
    const float* b2 = (const float*)d_in[7];
    const float* W3 = (const float*)d_in[8];
    const float* b3 = (const float*)d_in[9];
    const float* fw1 = (const float*)d_in[10];
    const float* fb1 = (const float*)d_in[11];
    const float* fw2 = (const float*)d_in[12];
    const float* fb2 = (const float*)d_in[13];
    const float* fw3 = (const float*)d_in[14];
    const float* fb3 = (const float*)d_in[15];
    float* out = (float*)d_out;

    const int* srcp = ei;
    const int* dstp = ei + NE;

    char* w = (char*)d_ws;
    size_t off = 0;
    auto take = [&](size_t bytes) -> char* {
        char* p = w + off;
        off += (bytes + 255) & ~size_t(255);
        return p;
    };
    int*   cnt       = (int*)take((size_t)NN * 4);
    int*   row_start = (int*)take((size_t)(NN + 1) * 4);
    int*   cursor    = (int*)take((size_t)NN * 4);
    int*   col       = (int*)take((size_t)NE * 4);
    float* dinv      = (float*)take((size_t)NN * 4);
    int*   bsum      = (int*)take((size_t)NB_SCAN * 4);
    int*   boff      = (int*)take((size_t)NB_SCAN * 4);
    int*   gstart    = (int*)take((size_t)(NG + 1) * 4);
    float* poolsum   = (float*)take((size_t)NG * F * 4);
    float* Wt        = (float*)take((size_t)F * F * 4);
    float* bufA      = (float*)take((size_t)NN * F * 4);
    float* bufB      = (float*)take((size_t)NN * F * 4);

    hipMemsetAsync(cnt, 0, (size_t)NN * 4, stream);
    hipMemsetAsync(poolsum, 0, (size_t)NG * F * 4, stream);

    k_count<<<(NE + 255) / 256, 256, 0, stream>>>(dstp, cnt);
    k_dinv<<<(NN + 255) / 256, 256, 0, stream>>>(cnt, dinv);
    k_scan1<<<NB_SCAN, 256, 0, stream>>>(cnt, bsum);
    k_scan2<<<1, 128, 0, stream>>>(bsum, boff);
    k_scan3<<<NB_SCAN, 256, 0, stream>>>(cnt, boff, row_start, cursor);
    k_scatter<<<(NE + 255) / 256, 256, 0, stream>>>(srcp, dstp, cursor, col);
    k_gstart<<<1, 128, 0, stream>>>(batch, gstart);

    hipFuncSetAttribute(reinterpret_cast<const void*>(k_gemm),
                        hipFuncAttributeMaxDynamicSharedMemorySize, GEMM_LDS);

    const int gemm_grid = (NN + TM - 1) / TM;

    // layer 1
    k_transpose<<<64, 256, 0, stream>>>(W1, Wt);
    k_gemm<<<gemm_grid, 256, GEMM_LDS, stream>>>(x, Wt, bufA);
    k_spmm<<<NN, F, 0, stream>>>(bufA, row_start, col, dinv, b1, bufB, 1);
    // layer 2
    k_transpose<<<64, 256, 0, stream>>>(W2, Wt);
    k_gemm<<<gemm_grid, 256, GEMM_LDS, stream>>>(bufB, Wt, bufA);
    k_spmm<<<NN, F, 0, stream>>>(bufA, row_start, col, dinv, b2, bufB, 1);
    // layer 3
    k_transpose<<<64, 256, 0, stream>>>(W3, Wt);
    k_gemm<<<gemm_grid, 256, GEMM_LDS, stream>>>(bufB, Wt, bufA);
    k_spmm<<<NN, F, 0, stream>>>(bufA, row_start, col, dinv, b3, bufB, 0);

    k_pool<<<NG * 16, F, 0, stream>>>(bufB, gstart, poolsum);
    k_mlp<<<NG, 64, 0, stream>>>(poolsum, gstart, stats, fw1, fb1, fw2, fb2, fw3, fb3, out);
}

// Round 2
// 604.609 us; speedup vs baseline: 1.8429x; 1.8429x over previous
//
#include <hip/hip_runtime.h>
#include <math.h>

#define NN 100000
#define NE 1600000
#define NG 64
#define F  128

constexpr int SCAN_CHUNK = 1024;                       // 256 threads * 4
constexpr int NB_SCAN = (NN + SCAN_CHUNK - 1) / SCAN_CHUNK;  // 98

typedef __bf16 bf16x8 __attribute__((ext_vector_type(8)));
typedef float  f32x4  __attribute__((ext_vector_type(4)));

__device__ __forceinline__ float b2f(unsigned short u) {
    union { unsigned i; float f; } v; v.i = ((unsigned)u) << 16; return v.f;
}
__device__ __forceinline__ unsigned short f2b(float f) {
    union { float f; unsigned i; } v; v.f = f;
    unsigned i = v.i;
    return (unsigned short)((i + 0x7fffu + ((i >> 16) & 1u)) >> 16);  // RNE
}

// ---------------- degree count ----------------
__global__ __launch_bounds__(256) void k_count(const int* __restrict__ dst, int* __restrict__ cnt) {
    int e = blockIdx.x * 256 + threadIdx.x;
    if (e < NE) atomicAdd(&cnt[dst[e]], 1);
}

__global__ __launch_bounds__(256) void k_dinv(const int* __restrict__ cnt, float* __restrict__ dinv) {
    int i = blockIdx.x * 256 + threadIdx.x;
    if (i < NN) dinv[i] = rsqrtf((float)cnt[i] + 1.0f);
}

// ---------------- prefix scan (3 kernels) ----------------
__global__ __launch_bounds__(256) void k_scan1(const int* __restrict__ cnt, int* __restrict__ bsum) {
    __shared__ int sh[256];
    int b = blockIdx.x, t = threadIdx.x;
    int base = b * SCAN_CHUNK + t * 4;
    int s = 0;
#pragma unroll
    for (int u = 0; u < 4; ++u) { int i = base + u; if (i < NN) s += cnt[i]; }
    sh[t] = s; __syncthreads();
    for (int d = 128; d > 0; d >>= 1) { if (t < d) sh[t] += sh[t + d]; __syncthreads(); }
    if (t == 0) bsum[b] = sh[0];
}

__global__ __launch_bounds__(128) void k_scan2(const int* __restrict__ bsum, int* __restrict__ boff) {
    __shared__ int sh[128];
    int t = threadIdx.x;
    int v = (t < NB_SCAN) ? bsum[t] : 0;
    sh[t] = v; __syncthreads();
    for (int d = 1; d < 128; d <<= 1) {
        int x = (t >= d) ? sh[t - d] : 0;
        __syncthreads();
        sh[t] += x;
        __syncthreads();
    }
    if (t < NB_SCAN) boff[t] = sh[t] - v;  // exclusive
}

__global__ __launch_bounds__(256) void k_scan3(const int* __restrict__ cnt, const int* __restrict__ boff,
                                               int* __restrict__ row_start, int* __restrict__ cursor) {
    __shared__ int sh[256];
    int b = blockIdx.x, t = threadIdx.x;
    int base = b * SCAN_CHUNK + t * 4;
    int v[4]; int sum = 0;
#pragma unroll
    for (int u = 0; u < 4; ++u) { int i = base + u; v[u] = (i < NN) ? cnt[i] : 0; sum += v[u]; }
    sh[t] = sum; __syncthreads();
    for (int d = 1; d < 256; d <<= 1) {
        int x = (t >= d) ? sh[t - d] : 0;
        __syncthreads();
        sh[t] += x;
        __syncthreads();
    }
    int run = boff[b] + (sh[t] - sum);
#pragma unroll
    for (int u = 0; u < 4; ++u) {
        int i = base + u;
        if (i < NN) { row_start[i] = run; cursor[i] = run; run += v[u]; }
    }
    if (b == 0 && t == 0) row_start[NN] = NE;
}

__global__ __launch_bounds__(256) void k_scatter(const int* __restrict__ src, const int* __restrict__ dst,
                                                 int* __restrict__ cursor, int* __restrict__ col) {
    int e = blockIdx.x * 256 + threadIdx.x;
    if (e < NE) {
        int d = dst[e];
        int p = atomicAdd(&cursor[d], 1);
        col[p] = src[e];
    }
}

// ---------------- fp32 -> bf16 conversion (x) ----------------
__global__ __launch_bounds__(256) void k_f2b(const float* __restrict__ in, unsigned short* __restrict__ out,
                                             int n4) {
    int idx = blockIdx.x * 256 + threadIdx.x;
    if (idx < n4) {
        float4 v = *(const float4*)&in[(size_t)idx * 4];
        ushort4 o;
        o.x = f2b(v.x); o.y = f2b(v.y); o.z = f2b(v.z); o.w = f2b(v.w);
        *(ushort4*)&out[(size_t)idx * 4] = o;
    }
}

// ---------------- W prep: Wt_bf16[n][k] = bf16(W[k][n]) ----------------
__global__ __launch_bounds__(256) void k_wprep(const float* __restrict__ W, unsigned short* __restrict__ Wt) {
    int idx = blockIdx.x * 256 + threadIdx.x;   // 16384
    int k = idx >> 7, n = idx & 127;
    Wt[n * F + k] = f2b(W[idx]);
}

// ---------------- MFMA GEMM: C[M,128] = A[M,128] @ W[128,128], all bf16 io, fp32 acc --------
// block: 128 rows, 4 waves (each wave 32 rows x 128 cols). W^T staged in LDS with XOR swizzle.
// A-fragments loaded directly global->VGPR (each A row read exactly once; 64B segments).
__global__ __launch_bounds__(256) void k_gemm_mfma(const unsigned short* __restrict__ A,
                                                   const unsigned short* __restrict__ Wt,
                                                   unsigned short* __restrict__ C) {
    __shared__ unsigned short Ws[F * F];  // 32 KB, swizzled: byte ^= (n&7)<<4
    int tid = threadIdx.x;
    int wid = tid >> 6;
    int lane = tid & 63;
    int l15 = lane & 15, l4 = lane >> 4;
    int row0 = blockIdx.x * 128 + wid * 32;

    // prefetch A fragments: mf in {0,1} (16-row halves), ks in 0..3 (K chunks of 32)
    bf16x8 af[2][4];
#pragma unroll
    for (int mf = 0; mf < 2; ++mf) {
        int r = row0 + mf * 16 + l15;
        if (r > NN - 1) r = NN - 1;
        const unsigned short* rp = A + (size_t)r * F;
#pragma unroll
        for (int ks = 0; ks < 4; ++ks)
            af[mf][ks] = *(const bf16x8*)(rp + ks * 32 + l4 * 8);
    }

    // stage Wt into LDS (swizzled)
#pragma unroll
    for (int p = 0; p < 8; ++p) {
        int idx16 = p * 256 + tid;          // 16-byte unit index, 2048 total
        int n = idx16 >> 4;
        float4 v = *(const float4*)((const char*)Wt + (size_t)idx16 * 16);
        *(float4*)((char*)Ws + (((unsigned)idx16 * 16) ^ (unsigned)((n & 7) << 4))) = v;
    }
    __syncthreads();

    f32x4 acc[2][8];
#pragma unroll
    for (int mf = 0; mf < 2; ++mf)
#pragma unroll
        for (int nf = 0; nf < 8; ++nf) acc[mf][nf] = (f32x4){0.f, 0.f, 0.f, 0.f};

#pragma unroll
    for (int ks = 0; ks < 4; ++ks) {
        bf16x8 bfr[8];
#pragma unroll
        for (int nf = 0; nf < 8; ++nf) {
            int n = nf * 16 + l15;
            unsigned byte = (unsigned)(n * 256 + ks * 64 + l4 * 16) ^ (unsigned)((n & 7) << 4);
            bfr[nf] = *(const bf16x8*)((const char*)Ws + byte);
        }
#pragma unroll
        for (int nf = 0; nf < 8; ++nf) {
            acc[0][nf] = __builtin_amdgcn_mfma_f32_16x16x32_bf16(af[0][ks], bfr[nf], acc[0][nf], 0, 0, 0);
            acc[1][nf] = __builtin_amdgcn_mfma_f32_16x16x32_bf16(af[1][ks], bfr[nf], acc[1][nf], 0, 0, 0);
        }
    }

    // write C (bf16). C/D layout: col = lane&15, row = (lane>>4)*4 + reg
#pragma unroll
    for (int mf = 0; mf < 2; ++mf)
#pragma unroll
        for (int reg = 0; reg < 4; ++reg) {
            int r = row0 + mf * 16 + l4 * 4 + reg;
            if (r < NN) {
#pragma unroll
                for (int nf = 0; nf < 8; ++nf)
                    C[(size_t)r * F + nf * 16 + l15] = f2b(acc[mf][nf][reg]);
            }
        }
}

// ---------------- SpMM aggregation + bias + optional ELU (bf16 io, fp32 acc) ----------------
// block = 1 node, 64 threads; thread t handles cols 2t, 2t+1 (4B gather per lane).
__global__ __launch_bounds__(64) void k_spmm(const unsigned short* __restrict__ xw,
                                             const int* __restrict__ row_start,
                                             const int* __restrict__ col,
                                             const float* __restrict__ dinv,
                                             const float* __restrict__ bias,
                                             unsigned short* __restrict__ hout,
                                             int do_elu) {
    int i = blockIdx.x;
    int t = threadIdx.x;
    int s = row_start[i], e = row_start[i + 1];
    float a0 = 0.f, a1 = 0.f;
    for (int p = s; p < e; ++p) {
        int j = col[p];
        float dj = dinv[j];
        unsigned u = *(const unsigned*)&xw[(size_t)j * F + t * 2];
        a0 += dj * b2f((unsigned short)(u & 0xffffu));
        a1 += dj * b2f((unsigned short)(u >> 16));
    }
    float di = dinv[i];
    unsigned us = *(const unsigned*)&xw[(size_t)i * F + t * 2];
    float v0 = di * (a0 + di * b2f((unsigned short)(us & 0xffffu))) + bias[t * 2];
    float v1 = di * (a1 + di * b2f((unsigned short)(us >> 16))) + bias[t * 2 + 1];
    if (do_elu) {
        v0 = (v0 > 0.f) ? v0 : (__expf(v0) - 1.f);
        v1 = (v1 > 0.f) ? v1 : (__expf(v1) - 1.f);
    }
    unsigned w = (unsigned)f2b(v0) | ((unsigned)f2b(v1) << 16);
    *(unsigned*)&hout[(size_t)i * F + t * 2] = w;
}

// ---------------- graph boundaries by binary search ----------------
__global__ __launch_bounds__(128) void k_gstart(const int* __restrict__ batch, int* __restrict__ gstart) {
    int g = threadIdx.x;
    if (g > NG) return;
    if (g == NG) { gstart[NG] = NN; return; }
    int lo = 0, hi = NN;
    while (lo < hi) { int mid = (lo + hi) >> 1; if (batch[mid] < g) lo = mid + 1; else hi = mid; }
    gstart[g] = lo;
}

// ---------------- mean pool (partial sums, atomic combine) ----------------
__global__ __launch_bounds__(128) void k_pool(const unsigned short* __restrict__ h,
                                              const int* __restrict__ gstart,
                                              float* __restrict__ poolsum) {
    int g = blockIdx.x >> 4, q = blockIdx.x & 15;
    int c = threadIdx.x;
    int s = gstart[g], e = gstart[g + 1];
    int n = e - s;
    int per = (n + 15) >> 4;
    int ss = s + q * per;
    int ee = min(ss + per, e);
    float acc = 0.f;
    for (int i = ss; i < ee; ++i) acc += b2f(h[(size_t)i * F + c]);
    atomicAdd(&poolsum[g * F + c], acc);
}

// ---------------- final MLP ----------------
__global__ __launch_bounds__(64) void k_mlp(const float* __restrict__ poolsum, const int* __restrict__ gstart,
                                            const float* __restrict__ stats,
                                            const float* __restrict__ fw1, const float* __restrict__ fb1,
                                            const float* __restrict__ fw2, const float* __restrict__ fb2,
                                            const float* __restrict__ fw3, const float* __restrict__ fb3,
                                            float* __restrict__ out) {
    __shared__ float gv[F + 8];
    __shared__ float h1[32];
    __shared__ float h2[16];
    int g = blockIdx.x, t = threadIdx.x;
    float cntf = fmaxf((float)(gstart[g + 1] - gstart[g]), 1.0f);
    for (int c = t; c < F; c += 64) gv[c] = poolsum[g * F + c] / cntf;
    if (t < 8) gv[F + t] = stats[g * 8 + t];
    __syncthreads();
    if (t < 32) {
        float a = fb1[t];
        for (int k = 0; k < F + 8; ++k) a += gv[k] * fw1[k * 32 + t];
        h1[t] = fmaxf(a, 0.f);
    }
    __syncthreads();
    if (t < 16) {
        float a = fb2[t];
        for (int k = 0; k < 32; ++k) a += h1[k] * fw2[k * 16 + t];
        h2[t] = fmaxf(a, 0.f);
    }
    __syncthreads();
    if (t == 0) {
        float a = fb3[0];
        for (int k = 0; k < 16; ++k) a += h2[k] * fw3[k];
        out[g] = a;
    }
}

extern "C" void kernel_launch(void* const* d_in, const int* in_sizes, int n_in,
                              void* d_out, int out_size, void* d_ws, size_t ws_size,
                              hipStream_t stream) {
    const float* x     = (const float*)d_in[0];
    const int*   ei    = (const int*)d_in[1];
    const int*   batch = (const int*)d_in[2];
    const float* stats = (const float*)d_in[3];
    const float* W1 = (const float*)d_in[4];
    const float* b1 = (const float*)d_in[5];
    const float* W2 = (const float*)d_in[6];
    const float* b2 = (const float*)d_in[7];
    const float* W3 = (const float*)d_in[8];
    const float* b3 = (const float*)d_in[9];
    const float* fw1 = (const float*)d_in[10];
    const float* fb1 = (const float*)d_in[11];
    const float* fw2 = (const float*)d_in[12];
    const float* fb2 = (const float*)d_in[13];
    const float* fw3 = (const float*)d_in[14];
    const float* fb3 = (const float*)d_in[15];
    float* out = (float*)d_out;

    const int* srcp = ei;
    const int* dstp = ei + NE;

    char* w = (char*)d_ws;
    size_t off = 0;
    auto take = [&](size_t bytes) -> char* {
        char* p = w + off;
        off += (bytes + 255) & ~size_t(255);
        return p;
    };
    int*   cnt       = (int*)take((size_t)NN * 4);
    int*   row_start = (int*)take((size_t)(NN + 1) * 4);
    int*   cursor    = (int*)take((size_t)NN * 4);
    int*   col       = (int*)take((size_t)NE * 4);
    float* dinv      = (float*)take((size_t)NN * 4);
    int*   bsum      = (int*)take((size_t)NB_SCAN * 4);
    int*   boff      = (int*)take((size_t)NB_SCAN * 4);
    int*   gstart    = (int*)take((size_t)(NG + 1) * 4);
    float* poolsum   = (float*)take((size_t)NG * F * 4);
    unsigned short* Wt   = (unsigned short*)take((size_t)F * F * 2);
    unsigned short* xb   = (unsigned short*)take((size_t)NN * F * 2);
    unsigned short* bufA = (unsigned short*)take((size_t)NN * F * 2);
    unsigned short* bufB = (unsigned short*)take((size_t)NN * F * 2);

    hipMemsetAsync(cnt, 0, (size_t)NN * 4, stream);
    hipMemsetAsync(poolsum, 0, (size_t)NG * F * 4, stream);

    k_count<<<(NE + 255) / 256, 256, 0, stream>>>(dstp, cnt);
    k_dinv<<<(NN + 255) / 256, 256, 0, stream>>>(cnt, dinv);
    k_scan1<<<NB_SCAN, 256, 0, stream>>>(cnt, bsum);
    k_scan2<<<1, 128, 0, stream>>>(bsum, boff);
    k_scan3<<<NB_SCAN, 256, 0, stream>>>(cnt, boff, row_start, cursor);
    k_scatter<<<(NE + 255) / 256, 256, 0, stream>>>(srcp, dstp, cursor, col);
    k_gstart<<<1, 128, 0, stream>>>(batch, gstart);
    k_f2b<<<(NN * F / 4 + 255) / 256, 256, 0, stream>>>(x, xb, NN * F / 4);

    const int gemm_grid = (NN + 127) / 128;

    // layer 1
    k_wprep<<<64, 256, 0, stream>>>(W1, Wt);
    k_gemm_mfma<<<gemm_grid, 256, 0, stream>>>(xb, Wt, bufA);
    k_spmm<<<NN, 64, 0, stream>>>(bufA, row_start, col, dinv, b1, bufB, 1);
    // layer 2
    k_wprep<<<64, 256, 0, stream>>>(W2, Wt);
    k_gemm_mfma<<<gemm_grid, 256, 0, stream>>>(bufB, Wt, bufA);
    k_spmm<<<NN, 64, 0, stream>>>(bufA, row_start, col, dinv, b2, bufB, 1);
    // layer 3
    k_wprep<<<64, 256, 0, stream>>>(W3, Wt);
    k_gemm_mfma<<<gemm_grid, 256, 0, stream>>>(bufB, Wt, bufA);
    k_spmm<<<NN, 64, 0, stream>>>(bufA, row_start, col, dinv, b3, bufB, 0);

    k_pool<<<NG * 16, F, 0, stream>>>(bufB, gstart, poolsum);
    k_mlp<<<NG, 64, 0, stream>>>(poolsum, gstart, stats, fw1, fb1, fw2, fb2, fw3, fb3, out);
}

// Round 3
// 548.519 us; speedup vs baseline: 2.0313x; 1.1023x over previous
//
#include <hip/hip_runtime.h>
#include <math.h>

#define NN 100000
#define NE 1600000
#define NG 64
#define F  128

constexpr int SCAN_CHUNK = 1024;                       // 256 threads * 4
constexpr int NB_SCAN = (NN + SCAN_CHUNK - 1) / SCAN_CHUNK;  // 98
constexpr int NPASS = 4;                               // scatter dst-range passes
constexpr int PASS_W = (NN + NPASS - 1) / NPASS;       // 25000 nodes per pass

typedef __bf16 bf16x8 __attribute__((ext_vector_type(8)));
typedef float  f32x4  __attribute__((ext_vector_type(4)));

__device__ __forceinline__ float b2f(unsigned short u) {
    union { unsigned i; float f; } v; v.i = ((unsigned)u) << 16; return v.f;
}
__device__ __forceinline__ unsigned short f2b(float f) {
    union { float f; unsigned i; } v; v.f = f;
    unsigned i = v.i;
    return (unsigned short)((i + 0x7fffu + ((i >> 16) & 1u)) >> 16);  // RNE
}

// ---------------- degree count ----------------
__global__ __launch_bounds__(256) void k_count(const int* __restrict__ dst, int* __restrict__ cnt) {
    int e = blockIdx.x * 256 + threadIdx.x;
    if (e < NE) atomicAdd(&cnt[dst[e]], 1);
}

__global__ __launch_bounds__(256) void k_dinv(const int* __restrict__ cnt, float* __restrict__ dinv) {
    int i = blockIdx.x * 256 + threadIdx.x;
    if (i < NN) dinv[i] = rsqrtf((float)cnt[i] + 1.0f);
}

// ---------------- prefix scan (3 kernels) ----------------
__global__ __launch_bounds__(256) void k_scan1(const int* __restrict__ cnt, int* __restrict__ bsum) {
    __shared__ int sh[256];
    int b = blockIdx.x, t = threadIdx.x;
    int base = b * SCAN_CHUNK + t * 4;
    int s = 0;
#pragma unroll
    for (int u = 0; u < 4; ++u) { int i = base + u; if (i < NN) s += cnt[i]; }
    sh[t] = s; __syncthreads();
    for (int d = 128; d > 0; d >>= 1) { if (t < d) sh[t] += sh[t + d]; __syncthreads(); }
    if (t == 0) bsum[b] = sh[0];
}

__global__ __launch_bounds__(128) void k_scan2(const int* __restrict__ bsum, int* __restrict__ boff) {
    __shared__ int sh[128];
    int t = threadIdx.x;
    int v = (t < NB_SCAN) ? bsum[t] : 0;
    sh[t] = v; __syncthreads();
    for (int d = 1; d < 128; d <<= 1) {
        int x = (t >= d) ? sh[t - d] : 0;
        __syncthreads();
        sh[t] += x;
        __syncthreads();
    }
    if (t < NB_SCAN) boff[t] = sh[t] - v;  // exclusive
}

__global__ __launch_bounds__(256) void k_scan3(const int* __restrict__ cnt, const int* __restrict__ boff,
                                               int* __restrict__ row_start, int* __restrict__ cursor) {
    __shared__ int sh[256];
    int b = blockIdx.x, t = threadIdx.x;
    int base = b * SCAN_CHUNK + t * 4;
    int v[4]; int sum = 0;
#pragma unroll
    for (int u = 0; u < 4; ++u) { int i = base + u; v[u] = (i < NN) ? cnt[i] : 0; sum += v[u]; }
    sh[t] = sum; __syncthreads();
    for (int d = 1; d < 256; d <<= 1) {
        int x = (t >= d) ? sh[t - d] : 0;
        __syncthreads();
        sh[t] += x;
        __syncthreads();
    }
    int run = boff[b] + (sh[t] - sum);
#pragma unroll
    for (int u = 0; u < 4; ++u) {
        int i = base + u;
        if (i < NN) { row_start[i] = run; cursor[i] = run; run += v[u]; }
    }
    if (b == 0 && t == 0) row_start[NN] = NE;
}

// ---------------- scatter, dst-partitioned into NPASS L2-resident windows ----------------
// blockIdx.x = pass * CHUNKS + chunk; blocks dispatch pass-major so concurrently-running
// blocks write the same 1.6MB col window (L2-resident), killing write-allocate HBM traffic.
__global__ __launch_bounds__(256) void k_scatter(const int* __restrict__ src, const int* __restrict__ dst,
                                                 int* __restrict__ cursor, int* __restrict__ col) {
    const int CHUNKS = (NE + 255) / 256;
    int pass = blockIdx.x / CHUNKS;
    int e = (blockIdx.x % CHUNKS) * 256 + threadIdx.x;
    if (e < NE) {
        int d = dst[e];
        if ((unsigned)(d - pass * PASS_W) < (unsigned)PASS_W) {
            int s = src[e];
            int p = atomicAdd(&cursor[d], 1);
            col[p] = s;
        }
    }
}

// ---------------- W prep: Wt_bf16[n][k] = bf16(W[k][n]) ----------------
__global__ __launch_bounds__(256) void k_wprep(const float* __restrict__ W, unsigned short* __restrict__ Wt) {
    int idx = blockIdx.x * 256 + threadIdx.x;   // 16384
    int k = idx >> 7, n = idx & 127;
    Wt[n * F + k] = f2b(W[idx]);
}

// ---------------- MFMA GEMM: C[r,:] = dinv[r] * (A[r,:] @ W), bf16 out, fp32 acc ----------
// block: 128 rows, 4 waves (each wave 32 rows x 128 cols). W^T staged in LDS, XOR swizzle.
// A-fragments loaded directly global->VGPR. FP32IN: A is fp32 (layer 1), else bf16.
template <bool FP32IN>
__global__ __launch_bounds__(256) void k_gemm_mfma(const void* __restrict__ Av,
                                                   const unsigned short* __restrict__ Wt,
                                                   const float* __restrict__ dinv,
                                                   unsigned short* __restrict__ C) {
    __shared__ unsigned short Ws[F * F];  // 32 KB, swizzled: byte ^= (n&7)<<4
    int tid = threadIdx.x;
    int wid = tid >> 6;
    int lane = tid & 63;
    int l15 = lane & 15, l4 = lane >> 4;
    int row0 = blockIdx.x * 128 + wid * 32;

    // prefetch A fragments: mf in {0,1} (16-row halves), ks in 0..3 (K chunks of 32)
    bf16x8 af[2][4];
#pragma unroll
    for (int mf = 0; mf < 2; ++mf) {
        int r = row0 + mf * 16 + l15;
        if (r > NN - 1) r = NN - 1;
        if (FP32IN) {
            const float* rp = (const float*)Av + (size_t)r * F;
#pragma unroll
            for (int ks = 0; ks < 4; ++ks) {
                float4 v0 = *(const float4*)(rp + ks * 32 + l4 * 8);
                float4 v1 = *(const float4*)(rp + ks * 32 + l4 * 8 + 4);
                bf16x8 a;
                a[0] = (__bf16)v0.x; a[1] = (__bf16)v0.y; a[2] = (__bf16)v0.z; a[3] = (__bf16)v0.w;
                a[4] = (__bf16)v1.x; a[5] = (__bf16)v1.y; a[6] = (__bf16)v1.z; a[7] = (__bf16)v1.w;
                af[mf][ks] = a;
            }
        } else {
            const unsigned short* rp = (const unsigned short*)Av + (size_t)r * F;
#pragma unroll
            for (int ks = 0; ks < 4; ++ks)
                af[mf][ks] = *(const bf16x8*)(rp + ks * 32 + l4 * 8);
        }
    }

    // stage Wt into LDS (swizzled)
#pragma unroll
    for (int p = 0; p < 8; ++p) {
        int idx16 = p * 256 + tid;          // 16-byte unit index, 2048 total
        int n = idx16 >> 4;
        float4 v = *(const float4*)((const char*)Wt + (size_t)idx16 * 16);
        *(float4*)((char*)Ws + (((unsigned)idx16 * 16) ^ (unsigned)((n & 7) << 4))) = v;
    }
    __syncthreads();

    f32x4 acc[2][8];
#pragma unroll
    for (int mf = 0; mf < 2; ++mf)
#pragma unroll
        for (int nf = 0; nf < 8; ++nf) acc[mf][nf] = (f32x4){0.f, 0.f, 0.f, 0.f};

#pragma unroll
    for (int ks = 0; ks < 4; ++ks) {
        bf16x8 bfr[8];
#pragma unroll
        for (int nf = 0; nf < 8; ++nf) {
            int n = nf * 16 + l15;
            unsigned byte = (unsigned)(n * 256 + ks * 64 + l4 * 16) ^ (unsigned)((n & 7) << 4);
            bfr[nf] = *(const bf16x8*)((const char*)Ws + byte);
        }
#pragma unroll
        for (int nf = 0; nf < 8; ++nf) {
            acc[0][nf] = __builtin_amdgcn_mfma_f32_16x16x32_bf16(af[0][ks], bfr[nf], acc[0][nf], 0, 0, 0);
            acc[1][nf] = __builtin_amdgcn_mfma_f32_16x16x32_bf16(af[1][ks], bfr[nf], acc[1][nf], 0, 0, 0);
        }
    }

    // write C (bf16, row-scaled by dinv). C/D layout: col = lane&15, row = (lane>>4)*4 + reg
#pragma unroll
    for (int mf = 0; mf < 2; ++mf)
#pragma unroll
        for (int reg = 0; reg < 4; ++reg) {
            int r = row0 + mf * 16 + l4 * 4 + reg;
            if (r < NN) {
                float di = dinv[r];
#pragma unroll
                for (int nf = 0; nf < 8; ++nf)
                    C[(size_t)r * F + nf * 16 + l15] = f2b(di * acc[mf][nf][reg]);
            }
        }
}

// ---------------- SpMM aggregation + bias + optional ELU (bf16 io, fp32 acc) ----------------
// xw rows are pre-scaled by dinv (fused in GEMM epilogue):
//   out[i] = dinv[i] * (sum_{j in N(i)} xw'[j] + xw'[i]) + b
// block = 1 node, 64 threads; thread t handles cols 2t, 2t+1 (4B gather per lane).
__global__ __launch_bounds__(64) void k_spmm(const unsigned short* __restrict__ xw,
                                             const int* __restrict__ row_start,
                                             const int* __restrict__ col,
                                             const float* __restrict__ dinv,
                                             const float* __restrict__ bias,
                                             unsigned short* __restrict__ hout,
                                             int do_elu) {
    int i = blockIdx.x;
    int t = threadIdx.x;
    int s = row_start[i], e = row_start[i + 1];
    float a0 = 0.f, a1 = 0.f;
    for (int p = s; p < e; ++p) {
        int j = col[p];
        unsigned u = *(const unsigned*)&xw[(size_t)j * F + t * 2];
        a0 += b2f((unsigned short)(u & 0xffffu));
        a1 += b2f((unsigned short)(u >> 16));
    }
    float di = dinv[i];
    unsigned us = *(const unsigned*)&xw[(size_t)i * F + t * 2];
    float v0 = di * (a0 + b2f((unsigned short)(us & 0xffffu))) + bias[t * 2];
    float v1 = di * (a1 + b2f((unsigned short)(us >> 16))) + bias[t * 2 + 1];
    if (do_elu) {
        v0 = (v0 > 0.f) ? v0 : (__expf(v0) - 1.f);
        v1 = (v1 > 0.f) ? v1 : (__expf(v1) - 1.f);
    }
    unsigned w = (unsigned)f2b(v0) | ((unsigned)f2b(v1) << 16);
    *(unsigned*)&hout[(size_t)i * F + t * 2] = w;
}

// ---------------- graph boundaries by binary search ----------------
__global__ __launch_bounds__(128) void k_gstart(const int* __restrict__ batch, int* __restrict__ gstart) {
    int g = threadIdx.x;
    if (g > NG) return;
    if (g == NG) { gstart[NG] = NN; return; }
    int lo = 0, hi = NN;
    while (lo < hi) { int mid = (lo + hi) >> 1; if (batch[mid] < g) lo = mid + 1; else hi = mid; }
    gstart[g] = lo;
}

// ---------------- mean pool (partial sums, atomic combine) ----------------
__global__ __launch_bounds__(128) void k_pool(const unsigned short* __restrict__ h,
                                              const int* __restrict__ gstart,
                                              float* __restrict__ poolsum) {
    int g = blockIdx.x >> 4, q = blockIdx.x & 15;
    int c = threadIdx.x;
    int s = gstart[g], e = gstart[g + 1];
    int n = e - s;
    int per = (n + 15) >> 4;
    int ss = s + q * per;
    int ee = min(ss + per, e);
    float acc = 0.f;
    for (int i = ss; i < ee; ++i) acc += b2f(h[(size_t)i * F + c]);
    atomicAdd(&poolsum[g * F + c], acc);
}

// ---------------- final MLP ----------------
__global__ __launch_bounds__(64) void k_mlp(const float* __restrict__ poolsum, const int* __restrict__ gstart,
                                            const float* __restrict__ stats,
                                            const float* __restrict__ fw1, const float* __restrict__ fb1,
                                            const float* __restrict__ fw2, const float* __restrict__ fb2,
                                            const float* __restrict__ fw3, const float* __restrict__ fb3,
                                            float* __restrict__ out) {
    __shared__ float gv[F + 8];
    __shared__ float h1[32];
    __shared__ float h2[16];
    int g = blockIdx.x, t = threadIdx.x;
    float cntf = fmaxf((float)(gstart[g + 1] - gstart[g]), 1.0f);
    for (int c = t; c < F; c += 64) gv[c] = poolsum[g * F + c] / cntf;
    if (t < 8) gv[F + t] = stats[g * 8 + t];
    __syncthreads();
    if (t < 32) {
        float a = fb1[t];
        for (int k = 0; k < F + 8; ++k) a += gv[k] * fw1[k * 32 + t];
        h1[t] = fmaxf(a, 0.f);
    }
    __syncthreads();
    if (t < 16) {
        float a = fb2[t];
        for (int k = 0; k < 32; ++k) a += h1[k] * fw2[k * 16 + t];
        h2[t] = fmaxf(a, 0.f);
    }
    __syncthreads();
    if (t == 0) {
        float a = fb3[0];
        for (int k = 0; k < 16; ++k) a += h2[k] * fw3[k];
        out[g] = a;
    }
}

extern "C" void kernel_launch(void* const* d_in, const int* in_sizes, int n_in,
                              void* d_out, int out_size, void* d_ws, size_t ws_size,
                              hipStream_t stream) {
    const float* x     = (const float*)d_in[0];
    const int*   ei    = (const int*)d_in[1];
    const int*   batch = (const int*)d_in[2];
    const float* stats = (const float*)d_in[3];
    const float* W1 = (const float*)d_in[4];
    const float* b1 = (const float*)d_in[5];
    const float* W2 = (const float*)d_in[6];
    const float* b2 = (const float*)d_in[7];
    const float* W3 = (const float*)d_in[8];
    const float* b3 = (const float*)d_in[9];
    const float* fw1 = (const float*)d_in[10];
    const float* fb1 = (const float*)d_in[11];
    const float* fw2 = (const float*)d_in[12];
    const float* fb2 = (const float*)d_in[13];
    const float* fw3 = (const float*)d_in[14];
    const float* fb3 = (const float*)d_in[15];
    float* out = (float*)d_out;

    const int* srcp = ei;
    const int* dstp = ei + NE;

    char* w = (char*)d_ws;
    size_t off = 0;
    auto take = [&](size_t bytes) -> char* {
        char* p = w + off;
        off += (bytes + 255) & ~size_t(255);
        return p;
    };
    int*   cnt       = (int*)take((size_t)NN * 4);
    int*   row_start = (int*)take((size_t)(NN + 1) * 4);
    int*   cursor    = (int*)take((size_t)NN * 4);
    int*   col       = (int*)take((size_t)NE * 4);
    float* dinv      = (float*)take((size_t)NN * 4);
    int*   bsum      = (int*)take((size_t)NB_SCAN * 4);
    int*   boff      = (int*)take((size_t)NB_SCAN * 4);
    int*   gstart    = (int*)take((size_t)(NG + 1) * 4);
    float* poolsum   = (float*)take((size_t)NG * F * 4);
    unsigned short* Wt   = (unsigned short*)take((size_t)F * F * 2);
    unsigned short* bufA = (unsigned short*)take((size_t)NN * F * 2);
    unsigned short* bufB = (unsigned short*)take((size_t)NN * F * 2);

    hipMemsetAsync(cnt, 0, (size_t)NN * 4, stream);
    hipMemsetAsync(poolsum, 0, (size_t)NG * F * 4, stream);

    k_count<<<(NE + 255) / 256, 256, 0, stream>>>(dstp, cnt);
    k_dinv<<<(NN + 255) / 256, 256, 0, stream>>>(cnt, dinv);
    k_scan1<<<NB_SCAN, 256, 0, stream>>>(cnt, bsum);
    k_scan2<<<1, 128, 0, stream>>>(bsum, boff);
    k_scan3<<<NB_SCAN, 256, 0, stream>>>(cnt, boff, row_start, cursor);
    const int chunks = (NE + 255) / 256;
    k_scatter<<<NPASS * chunks, 256, 0, stream>>>(srcp, dstp, cursor, col);
    k_gstart<<<1, 128, 0, stream>>>(batch, gstart);

    const int gemm_grid = (NN + 127) / 128;

    // layer 1 (fp32 input)
    k_wprep<<<64, 256, 0, stream>>>(W1, Wt);
    k_gemm_mfma<true><<<gemm_grid, 256, 0, stream>>>(x, Wt, dinv, bufA);
    k_spmm<<<NN, 64, 0, stream>>>(bufA, row_start, col, dinv, b1, bufB, 1);
    // layer 2
    k_wprep<<<64, 256, 0, stream>>>(W2, Wt);
    k_gemm_mfma<false><<<gemm_grid, 256, 0, stream>>>(bufB, Wt, dinv, bufA);
    k_spmm<<<NN, 64, 0, stream>>>(bufA, row_start, col, dinv, b2, bufB, 1);
    // layer 3
    k_wprep<<<64, 256, 0, stream>>>(W3, Wt);
    k_gemm_mfma<false><<<gemm_grid, 256, 0, stream>>>(bufB, Wt, dinv, bufA);
    k_spmm<<<NN, 64, 0, stream>>>(bufA, row_start, col, dinv, b3, bufB, 0);

    k_pool<<<NG * 16, F, 0, stream>>>(bufB, gstart, poolsum);
    k_mlp<<<NG, 64, 0, stream>>>(poolsum, gstart, stats, fw1, fb1, fw2, fb2, fw3, fb3, out);
}

// Round 4
// 454.603 us; speedup vs baseline: 2.4510x; 1.2066x over previous
//
#include <hip/hip_runtime.h>
#include <math.h>

#define NN 100000
#define NE 1600000
#define NG 64
#define F  128

constexpr int SCAN_CHUNK = 1024;                       // 256 threads * 4
constexpr int NB_SCAN = (NN + SCAN_CHUNK - 1) / SCAN_CHUNK;  // 98
constexpr int NPASS = 4;                               // scatter dst-range passes
constexpr int PASS_W = (NN + NPASS - 1) / NPASS;       // 25000 nodes per pass

typedef __bf16 bf16x8 __attribute__((ext_vector_type(8)));
typedef float  f32x4  __attribute__((ext_vector_type(4)));

__device__ __forceinline__ float b2f(unsigned short u) {
    union { unsigned i; float f; } v; v.i = ((unsigned)u) << 16; return v.f;
}
__device__ __forceinline__ float b2f_lo(unsigned u) {
    union { unsigned i; float f; } v; v.i = u << 16; return v.f;
}
__device__ __forceinline__ float b2f_hi(unsigned u) {
    union { unsigned i; float f; } v; v.i = u & 0xffff0000u; return v.f;
}
__device__ __forceinline__ unsigned short f2b(float f) {
    union { float f; unsigned i; } v; v.f = f;
    unsigned i = v.i;
    return (unsigned short)((i + 0x7fffu + ((i >> 16) & 1u)) >> 16);  // RNE
}

// ---------------- degree count ----------------
__global__ __launch_bounds__(256) void k_count(const int* __restrict__ dst, int* __restrict__ cnt) {
    int e = blockIdx.x * 256 + threadIdx.x;
    if (e < NE) atomicAdd(&cnt[dst[e]], 1);
}

__global__ __launch_bounds__(256) void k_dinv(const int* __restrict__ cnt, float* __restrict__ dinv) {
    int i = blockIdx.x * 256 + threadIdx.x;
    if (i < NN) dinv[i] = rsqrtf((float)cnt[i] + 1.0f);
}

// ---------------- prefix scan (3 kernels) ----------------
__global__ __launch_bounds__(256) void k_scan1(const int* __restrict__ cnt, int* __restrict__ bsum) {
    __shared__ int sh[256];
    int b = blockIdx.x, t = threadIdx.x;
    int base = b * SCAN_CHUNK + t * 4;
    int s = 0;
#pragma unroll
    for (int u = 0; u < 4; ++u) { int i = base + u; if (i < NN) s += cnt[i]; }
    sh[t] = s; __syncthreads();
    for (int d = 128; d > 0; d >>= 1) { if (t < d) sh[t] += sh[t + d]; __syncthreads(); }
    if (t == 0) bsum[b] = sh[0];
}

__global__ __launch_bounds__(128) void k_scan2(const int* __restrict__ bsum, int* __restrict__ boff) {
    __shared__ int sh[128];
    int t = threadIdx.x;
    int v = (t < NB_SCAN) ? bsum[t] : 0;
    sh[t] = v; __syncthreads();
    for (int d = 1; d < 128; d <<= 1) {
        int x = (t >= d) ? sh[t - d] : 0;
        __syncthreads();
        sh[t] += x;
        __syncthreads();
    }
    if (t < NB_SCAN) boff[t] = sh[t] - v;  // exclusive
}

__global__ __launch_bounds__(256) void k_scan3(const int* __restrict__ cnt, const int* __restrict__ boff,
                                               int* __restrict__ row_start, int* __restrict__ cursor) {
    __shared__ int sh[256];
    int b = blockIdx.x, t = threadIdx.x;
    int base = b * SCAN_CHUNK + t * 4;
    int v[4]; int sum = 0;
#pragma unroll
    for (int u = 0; u < 4; ++u) { int i = base + u; v[u] = (i < NN) ? cnt[i] : 0; sum += v[u]; }
    sh[t] = sum; __syncthreads();
    for (int d = 1; d < 256; d <<= 1) {
        int x = (t >= d) ? sh[t - d] : 0;
        __syncthreads();
        sh[t] += x;
        __syncthreads();
    }
    int run = boff[b] + (sh[t] - sum);
#pragma unroll
    for (int u = 0; u < 4; ++u) {
        int i = base + u;
        if (i < NN) { row_start[i] = run; cursor[i] = run; run += v[u]; }
    }
    if (b == 0 && t == 0) row_start[NN] = NE;
}

// ---------------- scatter, dst-partitioned into NPASS L2-resident windows ----------------
__global__ __launch_bounds__(256) void k_scatter(const int* __restrict__ src, const int* __restrict__ dst,
                                                 int* __restrict__ cursor, int* __restrict__ col) {
    const int CHUNKS = (NE + 255) / 256;
    int pass = blockIdx.x / CHUNKS;
    int e = (blockIdx.x % CHUNKS) * 256 + threadIdx.x;
    if (e < NE) {
        int d = dst[e];
        if ((unsigned)(d - pass * PASS_W) < (unsigned)PASS_W) {
            int s = src[e];
            int p = atomicAdd(&cursor[d], 1);
            col[p] = s;
        }
    }
}

// ---------------- W prep: Wt_bf16[n][k] = bf16(W[k][n]) ----------------
__global__ __launch_bounds__(256) void k_wprep(const float* __restrict__ W, unsigned short* __restrict__ Wt) {
    int idx = blockIdx.x * 256 + threadIdx.x;   // 16384
    int k = idx >> 7, n = idx & 127;
    Wt[n * F + k] = f2b(W[idx]);
}

// ---------------- MFMA GEMM: C[r,:] = dinv[r] * (A[r,:] @ W), bf16 out, fp32 acc ----------
template <bool FP32IN>
__global__ __launch_bounds__(256) void k_gemm_mfma(const void* __restrict__ Av,
                                                   const unsigned short* __restrict__ Wt,
                                                   const float* __restrict__ dinv,
                                                   unsigned short* __restrict__ C) {
    __shared__ unsigned short Ws[F * F];  // 32 KB, swizzled: byte ^= (n&7)<<4
    int tid = threadIdx.x;
    int wid = tid >> 6;
    int lane = tid & 63;
    int l15 = lane & 15, l4 = lane >> 4;
    int row0 = blockIdx.x * 128 + wid * 32;

    // prefetch A fragments: mf in {0,1} (16-row halves), ks in 0..3 (K chunks of 32)
    bf16x8 af[2][4];
#pragma unroll
    for (int mf = 0; mf < 2; ++mf) {
        int r = row0 + mf * 16 + l15;
        if (r > NN - 1) r = NN - 1;
        if (FP32IN) {
            const float* rp = (const float*)Av + (size_t)r * F;
#pragma unroll
            for (int ks = 0; ks < 4; ++ks) {
                float4 v0 = *(const float4*)(rp + ks * 32 + l4 * 8);
                float4 v1 = *(const float4*)(rp + ks * 32 + l4 * 8 + 4);
                bf16x8 a;
                a[0] = (__bf16)v0.x; a[1] = (__bf16)v0.y; a[2] = (__bf16)v0.z; a[3] = (__bf16)v0.w;
                a[4] = (__bf16)v1.x; a[5] = (__bf16)v1.y; a[6] = (__bf16)v1.z; a[7] = (__bf16)v1.w;
                af[mf][ks] = a;
            }
        } else {
            const unsigned short* rp = (const unsigned short*)Av + (size_t)r * F;
#pragma unroll
            for (int ks = 0; ks < 4; ++ks)
                af[mf][ks] = *(const bf16x8*)(rp + ks * 32 + l4 * 8);
        }
    }

    // stage Wt into LDS (swizzled)
#pragma unroll
    for (int p = 0; p < 8; ++p) {
        int idx16 = p * 256 + tid;          // 16-byte unit index, 2048 total
        int n = idx16 >> 4;
        float4 v = *(const float4*)((const char*)Wt + (size_t)idx16 * 16);
        *(float4*)((char*)Ws + (((unsigned)idx16 * 16) ^ (unsigned)((n & 7) << 4))) = v;
    }
    __syncthreads();

    f32x4 acc[2][8];
#pragma unroll
    for (int mf = 0; mf < 2; ++mf)
#pragma unroll
        for (int nf = 0; nf < 8; ++nf) acc[mf][nf] = (f32x4){0.f, 0.f, 0.f, 0.f};

#pragma unroll
    for (int ks = 0; ks < 4; ++ks) {
        bf16x8 bfr[8];
#pragma unroll
        for (int nf = 0; nf < 8; ++nf) {
            int n = nf * 16 + l15;
            unsigned byte = (unsigned)(n * 256 + ks * 64 + l4 * 16) ^ (unsigned)((n & 7) << 4);
            bfr[nf] = *(const bf16x8*)((const char*)Ws + byte);
        }
#pragma unroll
        for (int nf = 0; nf < 8; ++nf) {
            acc[0][nf] = __builtin_amdgcn_mfma_f32_16x16x32_bf16(af[0][ks], bfr[nf], acc[0][nf], 0, 0, 0);
            acc[1][nf] = __builtin_amdgcn_mfma_f32_16x16x32_bf16(af[1][ks], bfr[nf], acc[1][nf], 0, 0, 0);
        }
    }

    // write C (bf16, row-scaled by dinv). C/D layout: col = lane&15, row = (lane>>4)*4 + reg
#pragma unroll
    for (int mf = 0; mf < 2; ++mf)
#pragma unroll
        for (int reg = 0; reg < 4; ++reg) {
            int r = row0 + mf * 16 + l4 * 4 + reg;
            if (r < NN) {
                float di = dinv[r];
#pragma unroll
                for (int nf = 0; nf < 8; ++nf)
                    C[(size_t)r * F + nf * 16 + l15] = f2b(di * acc[mf][nf][reg]);
            }
        }
}

// ---------------- SpMM aggregation + bias + optional ELU (bf16 io, fp32 acc) ----------------
// xw rows pre-scaled by dinv. out[i] = dinv[i]*(sum_j xw'[j] + xw'[i]) + b.
// block = 1 node, 64 threads; thread t handles cols 2t,2t+1 (1 dword per lane).
// Edge loop unrolled 4-deep with clamped+masked tail: 4 independent gathers in
// flight per wave (latency-bound fix; round-3 profile showed 1-deep = 2.1 TB/s).
__global__ __launch_bounds__(64) void k_spmm(const unsigned short* __restrict__ xw,
                                             const int* __restrict__ row_start,
                                             const int* __restrict__ col,
                                             const float* __restrict__ dinv,
                                             const float* __restrict__ bias,
                                             unsigned short* __restrict__ hout,
                                             int do_elu) {
    int i = blockIdx.x;
    int t = threadIdx.x;
    int s = row_start[i], e = row_start[i + 1];
    const unsigned* base = (const unsigned*)xw;   // row j starts at dword j*64
    float a0 = 0.f, a1 = 0.f;
    for (int p = s; p < e; p += 4) {
        int p1 = (p + 1 < e) ? p + 1 : p;
        int p2 = (p + 2 < e) ? p + 2 : p;
        int p3 = (p + 3 < e) ? p + 3 : p;
        int j0 = col[p], j1 = col[p1], j2 = col[p2], j3 = col[p3];
        unsigned u0 = base[(size_t)j0 * 64 + t];
        unsigned u1 = base[(size_t)j1 * 64 + t];
        unsigned u2 = base[(size_t)j2 * 64 + t];
        unsigned u3 = base[(size_t)j3 * 64 + t];
        float m1 = (p + 1 < e) ? 1.f : 0.f;
        float m2 = (p + 2 < e) ? 1.f : 0.f;
        float m3 = (p + 3 < e) ? 1.f : 0.f;
        a0 += b2f_lo(u0) + m1 * b2f_lo(u1) + m2 * b2f_lo(u2) + m3 * b2f_lo(u3);
        a1 += b2f_hi(u0) + m1 * b2f_hi(u1) + m2 * b2f_hi(u2) + m3 * b2f_hi(u3);
    }
    float di = dinv[i];
    unsigned us = base[(size_t)i * 64 + t];
    float v0 = di * (a0 + b2f_lo(us)) + bias[t * 2];
    float v1 = di * (a1 + b2f_hi(us)) + bias[t * 2 + 1];
    if (do_elu) {
        v0 = (v0 > 0.f) ? v0 : (__expf(v0) - 1.f);
        v1 = (v1 > 0.f) ? v1 : (__expf(v1) - 1.f);
    }
    unsigned w = (unsigned)f2b(v0) | ((unsigned)f2b(v1) << 16);
    *(unsigned*)&hout[(size_t)i * F + t * 2] = w;
}

// ---------------- graph boundaries by binary search ----------------
__global__ __launch_bounds__(128) void k_gstart(const int* __restrict__ batch, int* __restrict__ gstart) {
    int g = threadIdx.x;
    if (g > NG) return;
    if (g == NG) { gstart[NG] = NN; return; }
    int lo = 0, hi = NN;
    while (lo < hi) { int mid = (lo + hi) >> 1; if (batch[mid] < g) lo = mid + 1; else hi = mid; }
    gstart[g] = lo;
}

// ---------------- mean pool (partial sums, atomic combine) ----------------
__global__ __launch_bounds__(128) void k_pool(const unsigned short* __restrict__ h,
                                              const int* __restrict__ gstart,
                                              float* __restrict__ poolsum) {
    int g = blockIdx.x >> 4, q = blockIdx.x & 15;
    int c = threadIdx.x;
    int s = gstart[g], e = gstart[g + 1];
    int n = e - s;
    int per = (n + 15) >> 4;
    int ss = s + q * per;
    int ee = min(ss + per, e);
    float acc = 0.f;
    for (int i = ss; i < ee; ++i) acc += b2f(h[(size_t)i * F + c]);
    atomicAdd(&poolsum[g * F + c], acc);
}

// ---------------- final MLP ----------------
__global__ __launch_bounds__(64) void k_mlp(const float* __restrict__ poolsum, const int* __restrict__ gstart,
                                            const float* __restrict__ stats,
                                            const float* __restrict__ fw1, const float* __restrict__ fb1,
                                            const float* __restrict__ fw2, const float* __restrict__ fb2,
                                            const float* __restrict__ fw3, const float* __restrict__ fb3,
                                            float* __restrict__ out) {
    __shared__ float gv[F + 8];
    __shared__ float h1[32];
    __shared__ float h2[16];
    int g = blockIdx.x, t = threadIdx.x;
    float cntf = fmaxf((float)(gstart[g + 1] - gstart[g]), 1.0f);
    for (int c = t; c < F; c += 64) gv[c] = poolsum[g * F + c] / cntf;
    if (t < 8) gv[F + t] = stats[g * 8 + t];
    __syncthreads();
    if (t < 32) {
        float a = fb1[t];
        for (int k = 0; k < F + 8; ++k) a += gv[k] * fw1[k * 32 + t];
        h1[t] = fmaxf(a, 0.f);
    }
    __syncthreads();
    if (t < 16) {
        float a = fb2[t];
        for (int k = 0; k < 32; ++k) a += h1[k] * fw2[k * 16 + t];
        h2[t] = fmaxf(a, 0.f);
    }
    __syncthreads();
    if (t == 0) {
        float a = fb3[0];
        for (int k = 0; k < 16; ++k) a += h2[k] * fw3[k];
        out[g] = a;
    }
}

extern "C" void kernel_launch(void* const* d_in, const int* in_sizes, int n_in,
                              void* d_out, int out_size, void* d_ws, size_t ws_size,
                              hipStream_t stream) {
    const float* x     = (const float*)d_in[0];
    const int*   ei    = (const int*)d_in[1];
    const int*   batch = (const int*)d_in[2];
    const float* stats = (const float*)d_in[3];
    const float* W1 = (const float*)d_in[4];
    const float* b1 = (const float*)d_in[5];
    const float* W2 = (const float*)d_in[6];
    const float* b2 = (const float*)d_in[7];
    const float* W3 = (const float*)d_in[8];
    const float* b3 = (const float*)d_in[9];
    const float* fw1 = (const float*)d_in[10];
    const float* fb1 = (const float*)d_in[11];
    const float* fw2 = (const float*)d_in[12];
    const float* fb2 = (const float*)d_in[13];
    const float* fw3 = (const float*)d_in[14];
    const float* fb3 = (const float*)d_in[15];
    float* out = (float*)d_out;

    const int* srcp = ei;
    const int* dstp = ei + NE;

    char* w = (char*)d_ws;
    size_t off = 0;
    auto take = [&](size_t bytes) -> char* {
        char* p = w + off;
        off += (bytes + 255) & ~size_t(255);
        return p;
    };
    int*   cnt       = (int*)take((size_t)NN * 4);
    int*   row_start = (int*)take((size_t)(NN + 1) * 4);
    int*   cursor    = (int*)take((size_t)NN * 4);
    int*   col       = (int*)take((size_t)NE * 4);
    float* dinv      = (float*)take((size_t)NN * 4);
    int*   bsum      = (int*)take((size_t)NB_SCAN * 4);
    int*   boff      = (int*)take((size_t)NB_SCAN * 4);
    int*   gstart    = (int*)take((size_t)(NG + 1) * 4);
    float* poolsum   = (float*)take((size_t)NG * F * 4);
    unsigned short* Wt   = (unsigned short*)take((size_t)F * F * 2);
    unsigned short* bufA = (unsigned short*)take((size_t)NN * F * 2);
    unsigned short* bufB = (unsigned short*)take((size_t)NN * F * 2);

    hipMemsetAsync(cnt, 0, (size_t)NN * 4, stream);
    hipMemsetAsync(poolsum, 0, (size_t)NG * F * 4, stream);

    k_count<<<(NE + 255) / 256, 256, 0, stream>>>(dstp, cnt);
    k_dinv<<<(NN + 255) / 256, 256, 0, stream>>>(cnt, dinv);
    k_scan1<<<NB_SCAN, 256, 0, stream>>>(cnt, bsum);
    k_scan2<<<1, 128, 0, stream>>>(bsum, boff);
    k_scan3<<<NB_SCAN, 256, 0, stream>>>(cnt, boff, row_start, cursor);
    const int chunks = (NE + 255) / 256;
    k_scatter<<<NPASS * chunks, 256, 0, stream>>>(srcp, dstp, cursor, col);
    k_gstart<<<1, 128, 0, stream>>>(batch, gstart);

    const int gemm_grid = (NN + 127) / 128;

    // layer 1 (fp32 input)
    k_wprep<<<64, 256, 0, stream>>>(W1, Wt);
    k_gemm_mfma<true><<<gemm_grid, 256, 0, stream>>>(x, Wt, dinv, bufA);
    k_spmm<<<NN, 64, 0, stream>>>(bufA, row_start, col, dinv, b1, bufB, 1);
    // layer 2
    k_wprep<<<64, 256, 0, stream>>>(W2, Wt);
    k_gemm_mfma<false><<<gemm_grid, 256, 0, stream>>>(bufB, Wt, dinv, bufA);
    k_spmm<<<NN, 64, 0, stream>>>(bufA, row_start, col, dinv, b2, bufB, 1);
    // layer 3
    k_wprep<<<64, 256, 0, stream>>>(W3, Wt);
    k_gemm_mfma<false><<<gemm_grid, 256, 0, stream>>>(bufB, Wt, dinv, bufA);
    k_spmm<<<NN, 64, 0, stream>>>(bufA, row_start, col, dinv, b3, bufB, 0);

    k_pool<<<NG * 16, F, 0, stream>>>(bufB, gstart, poolsum);
    k_mlp<<<NG, 64, 0, stream>>>(poolsum, gstart, stats, fw1, fb1, fw2, fb2, fw3, fb3, out);
}

// Round 5
// 437.636 us; speedup vs baseline: 2.5460x; 1.0388x over previous
//
#include <hip/hip_runtime.h>
#include <math.h>

#define NN 100000
#define NE 1600000
#define NG 64
#define F  128

constexpr int SCAN_CHUNK = 1024;                       // 256 threads * 4
constexpr int NB_SCAN = (NN + SCAN_CHUNK - 1) / SCAN_CHUNK;  // 98
constexpr int NPASS = 8;                               // one dst-window per XCD
constexpr int PASS_W = (NN + NPASS - 1) / NPASS;       // 12500 nodes per window

typedef __bf16 bf16x8 __attribute__((ext_vector_type(8)));
typedef float  f32x4  __attribute__((ext_vector_type(4)));

__device__ __forceinline__ float b2f(unsigned short u) {
    union { unsigned i; float f; } v; v.i = ((unsigned)u) << 16; return v.f;
}
__device__ __forceinline__ float b2f_lo(unsigned u) {
    union { unsigned i; float f; } v; v.i = u << 16; return v.f;
}
__device__ __forceinline__ float b2f_hi(unsigned u) {
    union { unsigned i; float f; } v; v.i = u & 0xffff0000u; return v.f;
}
__device__ __forceinline__ unsigned short f2b(float f) {
    union { float f; unsigned i; } v; v.f = f;
    unsigned i = v.i;
    return (unsigned short)((i + 0x7fffu + ((i >> 16) & 1u)) >> 16);  // RNE
}

// ---------------- degree count ----------------
__global__ __launch_bounds__(256) void k_count(const int* __restrict__ dst, int* __restrict__ cnt) {
    int e = blockIdx.x * 256 + threadIdx.x;
    if (e < NE) atomicAdd(&cnt[dst[e]], 1);
}

__global__ __launch_bounds__(256) void k_dinv(const int* __restrict__ cnt, float* __restrict__ dinv) {
    int i = blockIdx.x * 256 + threadIdx.x;
    if (i < NN) dinv[i] = rsqrtf((float)cnt[i] + 1.0f);
}

// ---------------- prefix scan (3 kernels) ----------------
__global__ __launch_bounds__(256) void k_scan1(const int* __restrict__ cnt, int* __restrict__ bsum) {
    __shared__ int sh[256];
    int b = blockIdx.x, t = threadIdx.x;
    int base = b * SCAN_CHUNK + t * 4;
    int s = 0;
#pragma unroll
    for (int u = 0; u < 4; ++u) { int i = base + u; if (i < NN) s += cnt[i]; }
    sh[t] = s; __syncthreads();
    for (int d = 128; d > 0; d >>= 1) { if (t < d) sh[t] += sh[t + d]; __syncthreads(); }
    if (t == 0) bsum[b] = sh[0];
}

__global__ __launch_bounds__(128) void k_scan2(const int* __restrict__ bsum, int* __restrict__ boff) {
    __shared__ int sh[128];
    int t = threadIdx.x;
    int v = (t < NB_SCAN) ? bsum[t] : 0;
    sh[t] = v; __syncthreads();
    for (int d = 1; d < 128; d <<= 1) {
        int x = (t >= d) ? sh[t - d] : 0;
        __syncthreads();
        sh[t] += x;
        __syncthreads();
    }
    if (t < NB_SCAN) boff[t] = sh[t] - v;  // exclusive
}

__global__ __launch_bounds__(256) void k_scan3(const int* __restrict__ cnt, const int* __restrict__ boff,
                                               int* __restrict__ row_start, int* __restrict__ cursor) {
    __shared__ int sh[256];
    int b = blockIdx.x, t = threadIdx.x;
    int base = b * SCAN_CHUNK + t * 4;
    int v[4]; int sum = 0;
#pragma unroll
    for (int u = 0; u < 4; ++u) { int i = base + u; v[u] = (i < NN) ? cnt[i] : 0; sum += v[u]; }
    sh[t] = sum; __syncthreads();
    for (int d = 1; d < 256; d <<= 1) {
        int x = (t >= d) ? sh[t - d] : 0;
        __syncthreads();
        sh[t] += x;
        __syncthreads();
    }
    int run = boff[b] + (sh[t] - sum);
#pragma unroll
    for (int u = 0; u < 4; ++u) {
        int i = base + u;
        if (i < NN) { row_start[i] = run; cursor[i] = run; run += v[u]; }
    }
    if (b == 0 && t == 0) row_start[NN] = NE;
}

// ---------------- scatter, XCD-owned dst windows ----------------
// pass = blockIdx & 7 -> round-robin XCD mapping binds each 12500-node dst window
// (and its ~0.8MB col region) to ONE XCD's L2, so every col line is dirtied by a
// single L2 -> writeback ~6.4MB total (round-4 profile: shared windows = 92MB).
__global__ __launch_bounds__(256) void k_scatter(const int* __restrict__ src, const int* __restrict__ dst,
                                                 int* __restrict__ cursor, int* __restrict__ col) {
    int pass = blockIdx.x & (NPASS - 1);
    int e = (blockIdx.x >> 3) * 256 + threadIdx.x;
    if (e < NE) {
        int d = dst[e];
        if ((unsigned)(d - pass * PASS_W) < (unsigned)PASS_W) {
            int s = src[e];
            int p = atomicAdd(&cursor[d], 1);
            col[p] = s;
        }
    }
}

// ---------------- W prep: Wt_bf16[n][k] = bf16(W[k][n]) ----------------
__global__ __launch_bounds__(256) void k_wprep(const float* __restrict__ W, unsigned short* __restrict__ Wt) {
    int idx = blockIdx.x * 256 + threadIdx.x;   // 16384
    int k = idx >> 7, n = idx & 127;
    Wt[n * F + k] = f2b(W[idx]);
}

// ---------------- MFMA GEMM: C[r,:] = dinv[r] * (A[r,:] @ W), bf16 out, fp32 acc ----------
template <bool FP32IN>
__global__ __launch_bounds__(256) void k_gemm_mfma(const void* __restrict__ Av,
                                                   const unsigned short* __restrict__ Wt,
                                                   const float* __restrict__ dinv,
                                                   unsigned short* __restrict__ C) {
    __shared__ unsigned short Ws[F * F];  // 32 KB, swizzled: byte ^= (n&7)<<4
    int tid = threadIdx.x;
    int wid = tid >> 6;
    int lane = tid & 63;
    int l15 = lane & 15, l4 = lane >> 4;
    int row0 = blockIdx.x * 128 + wid * 32;

    // prefetch A fragments: mf in {0,1} (16-row halves), ks in 0..3 (K chunks of 32)
    bf16x8 af[2][4];
#pragma unroll
    for (int mf = 0; mf < 2; ++mf) {
        int r = row0 + mf * 16 + l15;
        if (r > NN - 1) r = NN - 1;
        if (FP32IN) {
            const float* rp = (const float*)Av + (size_t)r * F;
#pragma unroll
            for (int ks = 0; ks < 4; ++ks) {
                float4 v0 = *(const float4*)(rp + ks * 32 + l4 * 8);
                float4 v1 = *(const float4*)(rp + ks * 32 + l4 * 8 + 4);
                bf16x8 a;
                a[0] = (__bf16)v0.x; a[1] = (__bf16)v0.y; a[2] = (__bf16)v0.z; a[3] = (__bf16)v0.w;
                a[4] = (__bf16)v1.x; a[5] = (__bf16)v1.y; a[6] = (__bf16)v1.z; a[7] = (__bf16)v1.w;
                af[mf][ks] = a;
            }
        } else {
            const unsigned short* rp = (const unsigned short*)Av + (size_t)r * F;
#pragma unroll
            for (int ks = 0; ks < 4; ++ks)
                af[mf][ks] = *(const bf16x8*)(rp + ks * 32 + l4 * 8);
        }
    }

    // stage Wt into LDS (swizzled)
#pragma unroll
    for (int p = 0; p < 8; ++p) {
        int idx16 = p * 256 + tid;          // 16-byte unit index, 2048 total
        int n = idx16 >> 4;
        float4 v = *(const float4*)((const char*)Wt + (size_t)idx16 * 16);
        *(float4*)((char*)Ws + (((unsigned)idx16 * 16) ^ (unsigned)((n & 7) << 4))) = v;
    }
    __syncthreads();

    f32x4 acc[2][8];
#pragma unroll
    for (int mf = 0; mf < 2; ++mf)
#pragma unroll
        for (int nf = 0; nf < 8; ++nf) acc[mf][nf] = (f32x4){0.f, 0.f, 0.f, 0.f};

#pragma unroll
    for (int ks = 0; ks < 4; ++ks) {
        bf16x8 bfr[8];
#pragma unroll
        for (int nf = 0; nf < 8; ++nf) {
            int n = nf * 16 + l15;
            unsigned byte = (unsigned)(n * 256 + ks * 64 + l4 * 16) ^ (unsigned)((n & 7) << 4);
            bfr[nf] = *(const bf16x8*)((const char*)Ws + byte);
        }
#pragma unroll
        for (int nf = 0; nf < 8; ++nf) {
            acc[0][nf] = __builtin_amdgcn_mfma_f32_16x16x32_bf16(af[0][ks], bfr[nf], acc[0][nf], 0, 0, 0);
            acc[1][nf] = __builtin_amdgcn_mfma_f32_16x16x32_bf16(af[1][ks], bfr[nf], acc[1][nf], 0, 0, 0);
        }
    }

    // write C (bf16, row-scaled by dinv). C/D layout: col = lane&15, row = (lane>>4)*4 + reg
#pragma unroll
    for (int mf = 0; mf < 2; ++mf)
#pragma unroll
        for (int reg = 0; reg < 4; ++reg) {
            int r = row0 + mf * 16 + l4 * 4 + reg;
            if (r < NN) {
                float di = dinv[r];
#pragma unroll
                for (int nf = 0; nf < 8; ++nf)
                    C[(size_t)r * F + nf * 16 + l15] = f2b(di * acc[mf][nf][reg]);
            }
        }
}

// ---------------- SpMM aggregation + bias + optional ELU (bf16 io, fp32 acc) ----------------
// xw rows pre-scaled by dinv. out[i] = dinv[i]*(sum_j xw'[j] + xw'[i]) + b.
// block = 1 node, 64 threads; thread t handles cols 2t,2t+1 (1 dword per lane).
// Edge loop unrolled 4-deep (4 independent gathers in flight per wave).
__global__ __launch_bounds__(64) void k_spmm(const unsigned short* __restrict__ xw,
                                             const int* __restrict__ row_start,
                                             const int* __restrict__ col,
                                             const float* __restrict__ dinv,
                                             const float* __restrict__ bias,
                                             unsigned short* __restrict__ hout,
                                             int do_elu) {
    int i = blockIdx.x;
    int t = threadIdx.x;
    int s = row_start[i], e = row_start[i + 1];
    const unsigned* base = (const unsigned*)xw;   // row j starts at dword j*64
    float a0 = 0.f, a1 = 0.f;
    for (int p = s; p < e; p += 4) {
        int p1 = (p + 1 < e) ? p + 1 : p;
        int p2 = (p + 2 < e) ? p + 2 : p;
        int p3 = (p + 3 < e) ? p + 3 : p;
        int j0 = col[p], j1 = col[p1], j2 = col[p2], j3 = col[p3];
        unsigned u0 = base[(size_t)j0 * 64 + t];
        unsigned u1 = base[(size_t)j1 * 64 + t];
        unsigned u2 = base[(size_t)j2 * 64 + t];
        unsigned u3 = base[(size_t)j3 * 64 + t];
        float m1 = (p + 1 < e) ? 1.f : 0.f;
        float m2 = (p + 2 < e) ? 1.f : 0.f;
        float m3 = (p + 3 < e) ? 1.f : 0.f;
        a0 += b2f_lo(u0) + m1 * b2f_lo(u1) + m2 * b2f_lo(u2) + m3 * b2f_lo(u3);
        a1 += b2f_hi(u0) + m1 * b2f_hi(u1) + m2 * b2f_hi(u2) + m3 * b2f_hi(u3);
    }
    float di = dinv[i];
    unsigned us = base[(size_t)i * 64 + t];
    float v0 = di * (a0 + b2f_lo(us)) + bias[t * 2];
    float v1 = di * (a1 + b2f_hi(us)) + bias[t * 2 + 1];
    if (do_elu) {
        v0 = (v0 > 0.f) ? v0 : (__expf(v0) - 1.f);
        v1 = (v1 > 0.f) ? v1 : (__expf(v1) - 1.f);
    }
    unsigned w = (unsigned)f2b(v0) | ((unsigned)f2b(v1) << 16);
    *(unsigned*)&hout[(size_t)i * F + t * 2] = w;
}

// ---------------- graph boundaries by binary search ----------------
__global__ __launch_bounds__(128) void k_gstart(const int* __restrict__ batch, int* __restrict__ gstart) {
    int g = threadIdx.x;
    if (g > NG) return;
    if (g == NG) { gstart[NG] = NN; return; }
    int lo = 0, hi = NN;
    while (lo < hi) { int mid = (lo + hi) >> 1; if (batch[mid] < g) lo = mid + 1; else hi = mid; }
    gstart[g] = lo;
}

// ---------------- mean pool (partial sums, atomic combine) ----------------
__global__ __launch_bounds__(128) void k_pool(const unsigned short* __restrict__ h,
                                              const int* __restrict__ gstart,
                                              float* __restrict__ poolsum) {
    int g = blockIdx.x >> 4, q = blockIdx.x & 15;
    int c = threadIdx.x;
    int s = gstart[g], e = gstart[g + 1];
    int n = e - s;
    int per = (n + 15) >> 4;
    int ss = s + q * per;
    int ee = min(ss + per, e);
    float acc = 0.f;
    for (int i = ss; i < ee; ++i) acc += b2f(h[(size_t)i * F + c]);
    atomicAdd(&poolsum[g * F + c], acc);
}

// ---------------- final MLP ----------------
__global__ __launch_bounds__(64) void k_mlp(const float* __restrict__ poolsum, const int* __restrict__ gstart,
                                            const float* __restrict__ stats,
                                            const float* __restrict__ fw1, const float* __restrict__ fb1,
                                            const float* __restrict__ fw2, const float* __restrict__ fb2,
                                            const float* __restrict__ fw3, const float* __restrict__ fb3,
                                            float* __restrict__ out) {
    __shared__ float gv[F + 8];
    __shared__ float h1[32];
    __shared__ float h2[16];
    int g = blockIdx.x, t = threadIdx.x;
    float cntf = fmaxf((float)(gstart[g + 1] - gstart[g]), 1.0f);
    for (int c = t; c < F; c += 64) gv[c] = poolsum[g * F + c] / cntf;
    if (t < 8) gv[F + t] = stats[g * 8 + t];
    __syncthreads();
    if (t < 32) {
        float a = fb1[t];
        for (int k = 0; k < F + 8; ++k) a += gv[k] * fw1[k * 32 + t];
        h1[t] = fmaxf(a, 0.f);
    }
    __syncthreads();
    if (t < 16) {
        float a = fb2[t];
        for (int k = 0; k < 32; ++k) a += h1[k] * fw2[k * 16 + t];
        h2[t] = fmaxf(a, 0.f);
    }
    __syncthreads();
    if (t == 0) {
        float a = fb3[0];
        for (int k = 0; k < 16; ++k) a += h2[k] * fw3[k];
        out[g] = a;
    }
}

extern "C" void kernel_launch(void* const* d_in, const int* in_sizes, int n_in,
                              void* d_out, int out_size, void* d_ws, size_t ws_size,
                              hipStream_t stream) {
    const float* x     = (const float*)d_in[0];
    const int*   ei    = (const int*)d_in[1];
    const int*   batch = (const int*)d_in[2];
    const float* stats = (const float*)d_in[3];
    const float* W1 = (const float*)d_in[4];
    const float* b1 = (const float*)d_in[5];
    const float* W2 = (const float*)d_in[6];
    const float* b2 = (const float*)d_in[7];
    const float* W3 = (const float*)d_in[8];
    const float* b3 = (const float*)d_in[9];
    const float* fw1 = (const float*)d_in[10];
    const float* fb1 = (const float*)d_in[11];
    const float* fw2 = (const float*)d_in[12];
    const float* fb2 = (const float*)d_in[13];
    const float* fw3 = (const float*)d_in[14];
    const float* fb3 = (const float*)d_in[15];
    float* out = (float*)d_out;

    const int* srcp = ei;
    const int* dstp = ei + NE;

    char* w = (char*)d_ws;
    size_t off = 0;
    auto take = [&](size_t bytes) -> char* {
        char* p = w + off;
        off += (bytes + 255) & ~size_t(255);
        return p;
    };
    int*   cnt       = (int*)take((size_t)NN * 4);
    int*   row_start = (int*)take((size_t)(NN + 1) * 4);
    int*   cursor    = (int*)take((size_t)NN * 4);
    int*   col       = (int*)take((size_t)NE * 4);
    float* dinv      = (float*)take((size_t)NN * 4);
    int*   bsum      = (int*)take((size_t)NB_SCAN * 4);
    int*   boff      = (int*)take((size_t)NB_SCAN * 4);
    int*   gstart    = (int*)take((size_t)(NG + 1) * 4);
    float* poolsum   = (float*)take((size_t)NG * F * 4);
    unsigned short* Wt   = (unsigned short*)take((size_t)F * F * 2);
    unsigned short* bufA = (unsigned short*)take((size_t)NN * F * 2);
    unsigned short* bufB = (unsigned short*)take((size_t)NN * F * 2);

    hipMemsetAsync(cnt, 0, (size_t)NN * 4, stream);
    hipMemsetAsync(poolsum, 0, (size_t)NG * F * 4, stream);

    k_count<<<(NE + 255) / 256, 256, 0, stream>>>(dstp, cnt);
    k_dinv<<<(NN + 255) / 256, 256, 0, stream>>>(cnt, dinv);
    k_scan1<<<NB_SCAN, 256, 0, stream>>>(cnt, bsum);
    k_scan2<<<1, 128, 0, stream>>>(bsum, boff);
    k_scan3<<<NB_SCAN, 256, 0, stream>>>(cnt, boff, row_start, cursor);
    const int chunks = (NE + 255) / 256;
    k_scatter<<<NPASS * chunks, 256, 0, stream>>>(srcp, dstp, cursor, col);
    k_gstart<<<1, 128, 0, stream>>>(batch, gstart);

    const int gemm_grid = (NN + 127) / 128;

    // layer 1 (fp32 input)
    k_wprep<<<64, 256, 0, stream>>>(W1, Wt);
    k_gemm_mfma<true><<<gemm_grid, 256, 0, stream>>>(x, Wt, dinv, bufA);
    k_spmm<<<NN, 64, 0, stream>>>(bufA, row_start, col, dinv, b1, bufB, 1);
    // layer 2
    k_wprep<<<64, 256, 0, stream>>>(W2, Wt);
    k_gemm_mfma<false><<<gemm_grid, 256, 0, stream>>>(bufB, Wt, dinv, bufA);
    k_spmm<<<NN, 64, 0, stream>>>(bufA, row_start, col, dinv, b2, bufB, 1);
    // layer 3
    k_wprep<<<64, 256, 0, stream>>>(W3, Wt);
    k_gemm_mfma<false><<<gemm_grid, 256, 0, stream>>>(bufB, Wt, dinv, bufA);
    k_spmm<<<NN, 64, 0, stream>>>(bufA, row_start, col, dinv, b3, bufB, 0);

    k_pool<<<NG * 16, F, 0, stream>>>(bufB, gstart, poolsum);
    k_mlp<<<NG, 64, 0, stream>>>(poolsum, gstart, stats, fw1, fb1, fw2, fb2, fw3, fb3, out);
}